// Round 7
// baseline (620.122 us; speedup 1.0000x reference)
//
#include <hip/hip_runtime.h>

// 2-layer LSTM (H=12), B=8192, T=1024 + 64 free-running steps.
// R7: 256 blocks x 4 waves; each block owns 32 elements as TWO independent
// 16-element chains (X, Y) that share weight registers. Both chains' step-t
// work sits between the same barriers -> their latency chains overlap at the
// instruction level (fixes the 2-blocks/CU barrier convoy that pinned
// VALUBusy at 52%).
// Merged read: cell2(t) and cell1(t+1) consume the SAME 48-B record
// [h1(t) | h2(t-1)], so ONE ds_read_b128 feeds BOTH MFMAs (A1 has zeros on
// the h2 k-slots). Interval = {barrier; read; MFMA x2; act x2; write x2}.
// Parity layout per chain: region[p] record for elem n at n*48 B:
//   slots 0-11 = h1 written with parity p, slots 12-23 = h2 written so the
//   parity-p reader sees h2(t-1). Interval t (p=t&1): read region[p], write
//   h2(t) and h1(t+1) into region[p^1]. Every RAW/WAR is 1-barrier-separated.
// Fragment maps (gfx950, dtype-independent, HW-verified):
//   A[m=lane&15][k=8*(lane>>4)+j], B[k=8*(lane>>4)+j][n=lane&15],
//   D[row=4*(lane>>4)+reg][col=lane&15].

typedef _Float16 v8h  __attribute__((ext_vector_type(8)));
typedef float    v4f  __attribute__((ext_vector_type(4)));

constexpr int H   = 12;
constexpr int T   = 1024;
constexpr int FUT = 64;
constexpr int TT  = T + FUT;   // 1088
constexpr int B   = 8192;

static __device__ __forceinline__ float fexp2(float x){ return __builtin_amdgcn_exp2f(x); }
static __device__ __forceinline__ float frcp (float x){ return __builtin_amdgcn_rcpf(x); }

__global__ __launch_bounds__(256, 1) void lstm_mfma_kernel(
    const float* __restrict__ input,
    const float* __restrict__ w_ih1, const float* __restrict__ w_hh1,
    const float* __restrict__ b_ih1, const float* __restrict__ b_hh1,
    const float* __restrict__ w_ih2, const float* __restrict__ w_hh2,
    const float* __restrict__ b_ih2, const float* __restrict__ b_hh2,
    const float* __restrict__ w_lin, const float* __restrict__ b_lin,
    float* __restrict__ out)
{
  const int tid  = threadIdx.x;
  const int w    = tid >> 6;        // wave id 0..3 -> units 3w..3w+2
  const int lane = tid & 63;
  const int g    = lane >> 4;       // k-slice group / D-row group
  const int n    = lane & 15;       // element column
  const int e0   = blockIdx.x * 32; // 32 elements per block (2 chains)

  const float L2E = 1.4426950408889634f;
  const float sc[4] = { -L2E, -L2E, 2.0f * L2E, -L2E };  // i,f,g,o prescale
  const float TWO_L2E = 2.885390081777927f;

  // ---------------- A fragments (static, prescaled, zero-padded) ----------
  v8h A1 = {0,0,0,0,0,0,0,0}, A2 = {0,0,0,0,0,0,0,0};
  {
    const int m = lane & 15;
    if (m < 12) {
      const int q = m & 3, u = 3 * w + (m >> 2);
      const float s = sc[q];
      const int grow = (q * 12 + u);
      #pragma unroll
      for (int j = 0; j < 8; ++j) {
        const int kk = 8 * g + j;
        if (kk < 12) {
          A1[j] = (_Float16)(s * w_hh1[grow * 12 + kk]);
          A2[j] = (_Float16)(s * w_ih2[grow * 12 + kk]);
        } else if (kk < 24) {
          A2[j] = (_Float16)(s * w_hh2[grow * 12 + (kk - 12)]);
        }
      }
    } else if (m == 15 && w == 3) {
      // y-row: w_lin against the h2 half (K slots 12..23)
      #pragma unroll
      for (int j = 0; j < 8; ++j) {
        const int kk = 8 * g + j;
        if (kk >= 12 && kk < 24) A2[j] = (_Float16)w_lin[kk - 12];
      }
    }
  }

  // ---------------- C bias fragments + x weights (D rows 4g+r) ------------
  v4f C1 = {0,0,0,0}, C2 = {0,0,0,0};
  float wi1s[4] = {0,0,0,0};
  const int uD = 3 * w + g;          // this lane's unit (valid when g<3)
  if (g < 3) {
    #pragma unroll
    for (int r = 0; r < 4; ++r) {
      C1[r]   = sc[r] * (b_ih1[r * 12 + uD] + b_hh1[r * 12 + uD]);
      C2[r]   = sc[r] * (b_ih2[r * 12 + uD] + b_hh2[r * 12 + uD]);
      wi1s[r] = sc[r] * w_ih1[r * 12 + uD];
    }
  }
  const float blin = b_lin[0];

  // ---------------- LDS: 2 chains x 2 parity regions x 416 f16 ------------
  __shared__ _Float16 hb[1664];      // 3328 bytes
  for (int i = tid; i < 1664; i += 256) hb[i] = (_Float16)0.0f;
  char* hbB = (char*)hb;

  // per-chain constants
  float c1s[2] = {0.f, 0.f}, c2s[2] = {0.f, 0.f};
  const float* xrow[2] = { input + (size_t)(e0 + n) * T,
                           input + (size_t)(e0 + 16 + n) * T };
  float*       yrow[2] = { out + (size_t)(e0 + n) * TT,
                           out + (size_t)(e0 + 16 + n) * TT };
  const bool   ylane = (w == 3) && (g == 3);
  const float  xl[2] = { xrow[0][T - 1], xrow[1][T - 1] };

  auto act = [&](float g0, float g1, float g2v, float g3, float& c) -> float {
    const float Ai = fexp2(g0);
    const float Af = fexp2(g1);
    const float Eg = fexp2(g2v);
    const float Ao = fexp2(g3);
    const float pf = 1.0f + Af;
    const float P  = (1.0f + Ai) * (1.0f + Eg);
    c = fmaf(c, P, (Eg - 1.0f) * pf) * frcp(P * pf);
    const float Ec = fexp2(TWO_L2E * c);
    return (Ec - 1.0f) * frcp((1.0f + Ao) * (1.0f + Ec));
  };

  __syncthreads();                   // zero-init visible

  // ---------------- prologue: h1(0) = act(bias + wi1*x(0)), h states 0 ----
  float4 xv[2];
  #pragma unroll
  for (int c = 0; c < 2; ++c) {
    xv[c] = *reinterpret_cast<const float4*>(xrow[c]);   // x(0..3)
    const float x0 = xv[c].x;
    const float h1o = act(fmaf(wi1s[0], x0, C1[0]), fmaf(wi1s[1], x0, C1[1]),
                          fmaf(wi1s[2], x0, C1[2]), fmaf(wi1s[3], x0, C1[3]),
                          c1s[c]);
    if (g < 3) hb[c * 832 + n * 24 + uD] = (_Float16)h1o;   // region[0], h1 slots
  }

  // interval t (parity p): read region[p] -> h2(t), h1(t+1) -> region[p^1]
  auto interval = [&](int c, int p, float xnext) -> float {
    v8h R = *(const v8h*)(hbB + c * 1664 + p * 832 + n * 48 + g * 16);
    v4f D2 = __builtin_amdgcn_mfma_f32_16x16x32_f16(A2, R, C2, 0, 0, 0);
    v4f D1 = __builtin_amdgcn_mfma_f32_16x16x32_f16(A1, R, C1, 0, 0, 0);
    const float yraw = D2[3];                    // w3/g3: y(t-1) pre-bias
    const float h2o = act(D2[0], D2[1], D2[2], D2[3], c2s[c]);
    const float h1o = act(fmaf(wi1s[0], xnext, D1[0]), fmaf(wi1s[1], xnext, D1[1]),
                          fmaf(wi1s[2], xnext, D1[2]), fmaf(wi1s[3], xnext, D1[3]),
                          c1s[c]);
    if (g < 3) {
      hb[c * 832 + (p ^ 1) * 416 + n * 24 + 12 + uD] = (_Float16)h2o;  // h2(t)
      hb[c * 832 + (p ^ 1) * 416 + n * 24 + uD]      = (_Float16)h1o;  // h1(t+1)
    }
    return yraw;
  };

  float yb[2][4] = {{0,0,0,0},{0,0,0,0}};

  for (int tb = 0; tb < TT; tb += 4) {
    // x(tb+1..tb+3) from current chunk; reload; x(tb+4) from next chunk
    float x1[2], x2[2], x3[2], x4[2];
    #pragma unroll
    for (int c = 0; c < 2; ++c) {
      x1[c] = xv[c].y; x2[c] = xv[c].z; x3[c] = xv[c].w;
      if (tb + 4 < T) xv[c] = *reinterpret_cast<const float4*>(xrow[c] + tb + 4);
      else            xv[c] = make_float4(xl[c], xl[c], xl[c], xl[c]);
      x4[c] = xv[c].x;
    }

    __syncthreads();
    yb[0][3] = interval(0, 0, x1[0]) + blin;     // yields y(tb-1)
    yb[1][3] = interval(1, 0, x1[1]) + blin;
    if (tb > 0 && ylane) {
      *reinterpret_cast<float4*>(yrow[0] + tb - 4) =
          make_float4(yb[0][0], yb[0][1], yb[0][2], yb[0][3]);
      *reinterpret_cast<float4*>(yrow[1] + tb - 4) =
          make_float4(yb[1][0], yb[1][1], yb[1][2], yb[1][3]);
    }
    __syncthreads();
    yb[0][0] = interval(0, 1, x2[0]) + blin;     // y(tb)
    yb[1][0] = interval(1, 1, x2[1]) + blin;
    __syncthreads();
    yb[0][1] = interval(0, 0, x3[0]) + blin;     // y(tb+1)
    yb[1][1] = interval(1, 0, x3[1]) + blin;
    __syncthreads();
    yb[0][2] = interval(0, 1, x4[0]) + blin;     // y(tb+2)
    yb[1][2] = interval(1, 1, x4[1]) + blin;
  }

  // ---------------- epilogue: y(TT-1) from h2(TT-1) in region[0] ----------
  __syncthreads();
  #pragma unroll
  for (int c = 0; c < 2; ++c) {
    v8h R = *(const v8h*)(hbB + c * 1664 + 0 * 832 + n * 48 + g * 16);
    v4f D2 = __builtin_amdgcn_mfma_f32_16x16x32_f16(A2, R, C2, 0, 0, 0);
    yb[c][3] = D2[3] + blin;
    if (ylane)
      *reinterpret_cast<float4*>(yrow[c] + TT - 4) =
          make_float4(yb[c][0], yb[c][1], yb[c][2], yb[c][3]);
  }
}

extern "C" void kernel_launch(void* const* d_in, const int* in_sizes, int n_in,
                              void* d_out, int out_size, void* d_ws, size_t ws_size,
                              hipStream_t stream) {
  const float* input = (const float*)d_in[0];
  const float* w_ih1 = (const float*)d_in[2];
  const float* w_hh1 = (const float*)d_in[3];
  const float* b_ih1 = (const float*)d_in[4];
  const float* b_hh1 = (const float*)d_in[5];
  const float* w_ih2 = (const float*)d_in[6];
  const float* w_hh2 = (const float*)d_in[7];
  const float* b_ih2 = (const float*)d_in[8];
  const float* b_hh2 = (const float*)d_in[9];
  const float* w_lin = (const float*)d_in[10];
  const float* b_lin = (const float*)d_in[11];
  float* out = (float*)d_out;

  dim3 grid(B / 32);   // 256 blocks x 4 waves; 2 chains of 16 elems per block
  dim3 block(256);
  hipLaunchKernelGGL(lstm_mfma_kernel, grid, block, 0, stream,
                     input, w_ih1, w_hh1, b_ih1, b_hh1,
                     w_ih2, w_hh2, b_ih2, b_hh2, w_lin, b_lin, out);
}